// Round 1
// baseline (336.507 us; speedup 1.0000x reference)
//
#include <hip/hip_runtime.h>

#define N_IMG 2048
#define SRC   64
#define PADW  32
#define HIN   128   // SRC + 2*PAD
#define WIN   128
#define TH    128
#define TW    128

__global__ __launch_bounds__(256) void affine_sample_kernel(
    const float* __restrict__ affine,
    const float* __restrict__ fill,
    const float* __restrict__ stroke,
    float* __restrict__ out)
{
    __shared__ float sF[SRC * SRC];   // 16 KB
    __shared__ float sS[SRC * SRC];   // 16 KB

    const int n = blockIdx.x;
    const float* __restrict__ fptr = fill   + (size_t)n * SRC * SRC;
    const float* __restrict__ sptr = stroke + (size_t)n * SRC * SRC;

    // Stage both source images into LDS with float4 loads (coalesced).
    for (int i = threadIdx.x; i < SRC * SRC / 4; i += 256) {
        reinterpret_cast<float4*>(sF)[i] = reinterpret_cast<const float4*>(fptr)[i];
        reinterpret_cast<float4*>(sS)[i] = reinterpret_cast<const float4*>(sptr)[i];
    }

    // Per-thread theta computation (6 reads broadcast from cache; cheap).
    const float t0 = affine[n * 6 + 0];
    const float t1 = affine[n * 6 + 1];
    const float t2 = affine[n * 6 + 2];
    const float t3 = affine[n * 6 + 3];
    const float t4 = affine[n * 6 + 4];
    const float t5 = affine[n * 6 + 5];
    const float a00 = 2.0f / (1.0f + expf(-t0));
    const float a11 = 2.0f / (1.0f + expf(-t1));
    const float a01 = 2.0f * tanhf(t2);
    const float a10 = 2.0f * tanhf(t3);
    const float a02 = tanhf(t4);
    const float a12 = tanhf(t5);

    __syncthreads();

    float* __restrict__ outF = out + (size_t)n * TH * TW;
    float* __restrict__ outS = out + (size_t)N_IMG * TH * TW + (size_t)n * TH * TW;

    // Each thread computes 4 consecutive pixels -> float4 stores.
    for (int q = threadIdx.x; q < TH * TW / 4; q += 256) {
        const int py  = q >> 5;          // q / (TW/4)
        const int pxb = (q & 31) << 2;   // base x of the 4-pixel group
        const float Y = ((float)py + 0.5f) * (2.0f / TH) - 1.0f;

        float4 rf, rs;
        float* rfp = &rf.x;
        float* rsp = &rs.x;

        #pragma unroll
        for (int j = 0; j < 4; ++j) {
            const int px = pxb + j;
            const float X = ((float)px + 0.5f) * (2.0f / TW) - 1.0f;
            const float gx = a00 * X + a01 * Y + a02;
            const float gy = a10 * X + a11 * Y + a12;
            const float ix = ((gx + 1.0f) * (float)WIN - 1.0f) * 0.5f;
            const float iy = ((gy + 1.0f) * (float)HIN - 1.0f) * 0.5f;

            const float x0f = floorf(ix);
            const float y0f = floorf(iy);
            const float wx = ix - x0f;
            const float wy = iy - y0f;

            // Shift padded coords into source coords: valid src index in [0, SRC).
            const int x0 = (int)x0f - PADW;
            const int y0 = (int)y0f - PADW;

            const float w00 = (1.0f - wx) * (1.0f - wy);
            const float w10 = wx * (1.0f - wy);
            const float w01 = (1.0f - wx) * wy;
            const float w11 = wx * wy;

            const bool xv0 = (unsigned)x0       < (unsigned)SRC;
            const bool xv1 = (unsigned)(x0 + 1) < (unsigned)SRC;
            const bool yv0 = (unsigned)y0       < (unsigned)SRC;
            const bool yv1 = (unsigned)(y0 + 1) < (unsigned)SRC;

            float f00 = 0.f, f10 = 0.f, f01 = 0.f, f11 = 0.f;
            float s00 = 0.f, s10 = 0.f, s01 = 0.f, s11 = 0.f;

            const int base0 = y0 * SRC + x0;
            if (yv0) {
                if (xv0) { f00 = sF[base0];     s00 = sS[base0];     }
                if (xv1) { f10 = sF[base0 + 1]; s10 = sS[base0 + 1]; }
            }
            if (yv1) {
                const int base1 = base0 + SRC;
                if (xv0) { f01 = sF[base1];     s01 = sS[base1];     }
                if (xv1) { f11 = sF[base1 + 1]; s11 = sS[base1 + 1]; }
            }

            rfp[j] = f00 * w00 + f10 * w10 + f01 * w01 + f11 * w11;
            rsp[j] = s00 * w00 + s10 * w10 + s01 * w01 + s11 * w11;
        }

        reinterpret_cast<float4*>(outF)[q] = rf;
        reinterpret_cast<float4*>(outS)[q] = rs;
    }
}

extern "C" void kernel_launch(void* const* d_in, const int* in_sizes, int n_in,
                              void* d_out, int out_size, void* d_ws, size_t ws_size,
                              hipStream_t stream) {
    const float* affine = (const float*)d_in[0];  // (N, 6)
    const float* fill   = (const float*)d_in[1];  // (N, 64, 64)
    const float* stroke = (const float*)d_in[2];  // (N, 64, 64)
    // d_in[3] = targetsize, unused by the computation.
    float* out = (float*)d_out;                   // fill_out then stroke_out, each (N,128,128)

    affine_sample_kernel<<<dim3(N_IMG), dim3(256), 0, stream>>>(affine, fill, stroke, out);
}